// Round 11
// baseline (138.961 us; speedup 1.0000x reference)
//
#include <hip/hip_runtime.h>
#include <math.h>

// Fbank via split-bf16 MFMA + real-DFT folding. R11 = R10 with corrected
// LDS swizzles: 272-B-stride tiles use NO XOR (row base bank = 4r mod 32 is
// already 2-way-optimal; R10's added XOR collapsed it to 4-way = 8.47M
// conflicts). 320-stride keeps ((r>>1)&3)<<4; 512-stride keeps (r&7)<<4.

#define BATCH 32
#define TLEN 480000
#define NFRAMES 2998
#define FL 400
#define FS 160
#define PW 512
#define NM 80
#define MT 32                // frames per block
#define NTILES 94            // ceil(2998/32)
#define PRE 0.97f
#define EPSF 1e-6f

#define RE_KS 9              // K=288 (t 0..256 + pad)
#define IM_KS 8              // K=256 (t 0..255)
#define RE_U16 (16 * RE_KS * 64 * 8)   // 73728
#define IM_U16 (16 * IM_KS * 64 * 8)   // 65536
#define MEL_U16 (6 * 8 * 64 * 8)       // 24576
#define OFF_REH 0
#define OFF_REL RE_U16
#define OFF_IMH (2 * RE_U16)
#define OFF_IML (2 * RE_U16 + IM_U16)
#define OFF_MEL (2 * RE_U16 + 2 * IM_U16)
#define WS_NEED ((size_t)(OFF_MEL + MEL_U16) * 2)   // 606,208 B

// LDS tile byte offsets. 128-col tiles: 272-B row stride (natural bank
// rotation, no XOR). 160-col chunk1 s-tile: 320-B stride + SWT1 XOR.
#define C0_SH 0
#define C0_SL 8704
#define C0_DH 17408
#define C0_DL 26112          // chunk0 total 34,816 B
#define C1_SH 0
#define C1_SL 10240
#define C1_DH 20480
#define C1_DL 29184          // chunk1 total 37,888 B

typedef short bf16x8 __attribute__((ext_vector_type(8)));
typedef float f32x4 __attribute__((ext_vector_type(4)));
typedef unsigned int u32;
typedef unsigned short u16;
typedef u32 u32x4 __attribute__((ext_vector_type(4)));

__device__ __forceinline__ u16 f2bf(float f) {
    u32 u = __builtin_bit_cast(u32, f);
    return (u16)((u + 0x7FFFu + ((u >> 16) & 1u)) >> 16);
}
__device__ __forceinline__ float bf2f(u16 h) {
    u32 u = ((u32)h) << 16;
    return __builtin_bit_cast(float, u);
}

// ---------------- prep: pack folded B (cos K=288, sin K=256, hi+lo) + mel ----------------
__global__ void prep_kernel(const float* __restrict__ dftr, const float* __restrict__ dfti,
                            const float* __restrict__ melw, u16* __restrict__ wsb) {
    int idx = blockIdx.x * 256 + threadIdx.x;
    if (idx < 16 * RE_KS * 64) {                       // 9216 Re groups
        int nf = idx / (RE_KS * 64);
        int rem = idx - nf * (RE_KS * 64);
        int ks = rem >> 6, l = rem & 63;
        int f = nf * 16 + (l & 15);
        int k = ks * 32 + ((l >> 4) << 3);
        u16* dh = wsb + OFF_REH + (size_t)idx * 8;
        u16* dl = wsb + OFF_REL + (size_t)idx * 8;
        #pragma unroll
        for (int e = 0; e < 8; ++e) {
            int kk = k + e;
            float x = (kk <= 256) ? dftr[(size_t)f * PW + kk] : 0.f;
            u16 h = f2bf(x);
            dh[e] = h;
            dl[e] = f2bf(x - bf2f(h));
        }
    } else if (idx < 16 * RE_KS * 64 + 16 * IM_KS * 64) {   // 8192 Im groups
        int j = idx - 16 * RE_KS * 64;
        int nf = j / (IM_KS * 64);
        int rem = j - nf * (IM_KS * 64);
        int ks = rem >> 6, l = rem & 63;
        int f = nf * 16 + (l & 15);
        int k = ks * 32 + ((l >> 4) << 3);
        u16* dh = wsb + OFF_IMH + (size_t)j * 8;
        u16* dl = wsb + OFF_IML + (size_t)j * 8;
        #pragma unroll
        for (int e = 0; e < 8; ++e) {
            float x = dfti[(size_t)f * PW + k + e];    // k+e <= 255
            u16 h = f2bf(x);
            dh[e] = h;
            dl[e] = f2bf(x - bf2f(h));
        }
    } else {                                            // 3072 mel groups
        int m = idx - (16 * RE_KS * 64 + 16 * IM_KS * 64);
        if (m < 6 * 8 * 64) {
            int nf = m / (8 * 64);
            int ks = (m >> 6) & 7, l = m & 63;
            int n = nf * 16 + (l & 15);
            int k = ks * 32 + ((l >> 4) << 3);
            u16* dst = wsb + OFF_MEL + (size_t)m * 8;
            #pragma unroll
            for (int e = 0; e < 8; ++e)
                dst[e] = (n < NM) ? f2bf(melw[(size_t)n * 257 + k + e]) : (u16)0;
        }
    }
}

// swizzle select: 0 -> (r&7)<<4 (512-B stride), 1 -> ((r>>1)&3)<<4 (320-B), 2 -> none (272-B)
__device__ __forceinline__ u32 swz(int SWT, u32 r) {
    return (SWT == 0) ? ((r & 7u) << 4) : (SWT == 1) ? (((r >> 1) & 3u) << 4) : 0u;
}

// ---------------- DFT pass: 3-term split product over one A-tile chunk ----------------
template<int RS, int SWT, int NKS, int BKS>
__device__ __forceinline__ void dft_pass(
    const char* tH, const char* tL,
    const u16* __restrict__ bH, const u16* __restrict__ bL,
    int ks0, int g, int lane, f32x4 (&acc)[2][4]) {
    #pragma unroll
    for (int ks = 0; ks < NKS; ++ks) {
        bf16x8 aH[2], aL[2];
        #pragma unroll
        for (int mf = 0; mf < 2; ++mf) {
            u32 r = (u32)(mf * 16 + (lane & 15));
            u32 off = (u32)(ks * 64 + ((lane >> 4) << 4));
            u32 byte = r * RS + (off ^ swz(SWT, r));
            aH[mf] = *(const bf16x8*)(tH + byte);
            aL[mf] = *(const bf16x8*)(tL + byte);
        }
        #pragma unroll
        for (int j = 0; j < 4; ++j) {
            size_t o = ((size_t)((4 * g + j) * BKS + ks0 + ks) * 64 + lane) * 8;
            bf16x8 bh = *(const bf16x8*)(bH + o);
            bf16x8 bl = *(const bf16x8*)(bL + o);
            #pragma unroll
            for (int mf = 0; mf < 2; ++mf) {
                acc[mf][j] = __builtin_amdgcn_mfma_f32_16x16x32_bf16(aH[mf], bh, acc[mf][j], 0, 0, 0);
                acc[mf][j] = __builtin_amdgcn_mfma_f32_16x16x32_bf16(aL[mf], bh, acc[mf][j], 0, 0, 0);
                acc[mf][j] = __builtin_amdgcn_mfma_f32_16x16x32_bf16(aH[mf], bl, acc[mf][j], 0, 0, 0);
            }
        }
    }
}

__device__ __forceinline__ void pack_write(const float* ys, char* baseH, char* baseL, u32 byte) {
    u32x4 hv, lv;
    #pragma unroll
    for (int e = 0; e < 4; ++e) {
        u16 h0 = f2bf(ys[2 * e]), h1 = f2bf(ys[2 * e + 1]);
        hv[e] = (u32)h0 | ((u32)h1 << 16);
        u16 l0 = f2bf(ys[2 * e] - bf2f(h0)), l1 = f2bf(ys[2 * e + 1] - bf2f(h1));
        lv[e] = (u32)l0 | ((u32)l1 << 16);
    }
    *(u32x4*)(baseH + byte) = hv;
    *(u32x4*)(baseL + byte) = lv;
}

// ---------------- main fused kernel ----------------
__global__ __launch_bounds__(256, 3) void fbank_mfma(
    const float* __restrict__ wave, const float* __restrict__ win,
    const u16* __restrict__ wsb, float* __restrict__ out) {
    __shared__ float smean[MT];
    __shared__ u16 stile[18944];       // 37,888 B tile buffer (power overlay fits)
    char* T = (char*)stile;

    const int tid = threadIdx.x, w = tid >> 6, lane = tid & 63;
    const int q = lane >> 4;           // frame sub-row within step
    const int cg = lane & 15;          // col-group
    const int b = blockIdx.y;
    const int f0 = blockIdx.x * MT;
    const float* wb = wave + (size_t)b * TLEN;
    const float4* win4 = (const float4*)win;

    // ---- means -> LDS (2 steps x 4 frames per wave) ----
    #pragma unroll
    for (int i = 0; i < 2; ++i) {
        const int rr = w * 8 + i * 4 + q;
        const int fr = f0 + rr;
        float acc = 0.f;
        if (fr < NFRAMES) {
            const float4* x4 = (const float4*)(wb + (size_t)fr * FS);
            #pragma unroll
            for (int m = 0; m < 6; ++m) {
                float4 a = x4[cg + 16 * m];
                acc += a.x + a.y + a.z + a.w;
            }
            if (cg < 4) { float4 a = x4[96 + cg]; acc += a.x + a.y + a.z + a.w; }
        }
        #pragma unroll
        for (int o = 8; o; o >>= 1) acc += __shfl_xor(acc, o);
        if (cg == 0) smean[rr] = acc * (1.0f / FL);
    }
    __syncthreads();

    // ---- P1b: chunk0 (t 0..127): build s,d tiles (272-B stride, no XOR) ----
    #pragma unroll
    for (int i = 0; i < 2; ++i) {
        const int rr = w * 8 + i * 4 + q;
        const int fr = f0 + rr;
        const bool valid = fr < NFRAMES;
        const float* x = wb + (size_t)fr * FS;
        const float4* x4 = (const float4*)x;
        const float mc = (1.0f - PRE) * smean[rr];

        float4 v0 = {0,0,0,0}, v1 = {0,0,0,0};
        if (valid) { v0 = x4[2 * cg]; v1 = x4[2 * cg + 1]; }
        float4 w0 = win4[2 * cg], w1 = win4[2 * cg + 1];
        float xpn = __shfl(v1.w, lane - 1);
        float xprev = (cg == 0) ? v0.x : xpn;
        float y[8];
        y[0] = (v0.x - PRE * xprev - mc) * w0.x;
        y[1] = (v0.y - PRE * v0.x - mc) * w0.y;
        y[2] = (v0.z - PRE * v0.y - mc) * w0.z;
        y[3] = (v0.w - PRE * v0.z - mc) * w0.w;
        y[4] = (v1.x - PRE * v0.w - mc) * w1.x;
        y[5] = (v1.y - PRE * v1.x - mc) * w1.y;
        y[6] = (v1.z - PRE * v1.y - mc) * w1.z;
        y[7] = (v1.w - PRE * v1.z - mc) * w1.w;

        float yr[8];
        #pragma unroll
        for (int e = 0; e < 8; ++e) yr[e] = 0.f;
        if (cg >= 14) {                      // t >= 113 folds (u = 512-t in 385..399)
            const int u0 = 512 - 8 * cg;     // 400 (cg14) or 392 (cg15)
            float4 xr0 = {0,0,0,0}, xr1 = {0,0,0,0};
            float xu0 = 0.f;
            if (valid) {
                xr0 = x4[u0 / 4 - 2]; xr1 = x4[u0 / 4 - 1];
                if (u0 <= 399) xu0 = x[u0];
            }
            float4 wr0 = win4[u0 / 4 - 2], wr1 = win4[u0 / 4 - 1];
            float wu0 = (u0 <= 399) ? win[u0] : 0.f;
            yr[0] = (xu0   - PRE * xr1.w - mc) * wu0;
            yr[1] = (xr1.w - PRE * xr1.z - mc) * wr1.w;
            yr[2] = (xr1.z - PRE * xr1.y - mc) * wr1.z;
            yr[3] = (xr1.y - PRE * xr1.x - mc) * wr1.y;
            yr[4] = (xr1.x - PRE * xr0.w - mc) * wr1.x;
            yr[5] = (xr0.w - PRE * xr0.z - mc) * wr0.w;
            yr[6] = (xr0.z - PRE * xr0.y - mc) * wr0.z;
            yr[7] = (xr0.y - PRE * xr0.x - mc) * wr0.y;
        }
        float s8[8], d8[8];
        #pragma unroll
        for (int e = 0; e < 8; ++e) { s8[e] = y[e] + yr[e]; d8[e] = y[e] - yr[e]; }
        u32 byte = (u32)rr * 272u + (u32)cg * 16u;
        pack_write(s8, T + C0_SH, T + C0_SL, byte);
        pack_write(d8, T + C0_DH, T + C0_DL, byte);
    }
    __syncthreads();

    // ---- GEMM chunk0: Re ks 0..3 (A=s), Im ks 0..3 (A=d) ----
    const int g = w;
    f32x4 accR[2][4], accI[2][4];
    #pragma unroll
    for (int mf = 0; mf < 2; ++mf)
        #pragma unroll
        for (int j = 0; j < 4; ++j) { accR[mf][j] = (f32x4)0.f; accI[mf][j] = (f32x4)0.f; }

    dft_pass<272, 2, 4, RE_KS>(T + C0_SH, T + C0_SL, wsb + OFF_REH, wsb + OFF_REL, 0, g, lane, accR);
    dft_pass<272, 2, 4, IM_KS>(T + C0_DH, T + C0_DL, wsb + OFF_IMH, wsb + OFF_IML, 0, g, lane, accI);
    __syncthreads();

    // ---- P1c: chunk1 (t 128..255 fold; s also t 256..287 tail) ----
    #pragma unroll
    for (int i = 0; i < 2; ++i) {
        const int rr = w * 8 + i * 4 + q;
        const int fr = f0 + rr;
        const bool valid = fr < NFRAMES;
        const float* x = wb + (size_t)fr * FS;
        const float4* x4 = (const float4*)x;
        const float mc = (1.0f - PRE) * smean[rr];

        float4 v0 = {0,0,0,0}, v1 = {0,0,0,0};
        if (valid) { v0 = x4[32 + 2 * cg]; v1 = x4[33 + 2 * cg]; }
        float4 w0 = win4[32 + 2 * cg], w1 = win4[33 + 2 * cg];
        float xpn = __shfl(v1.w, lane - 1);
        float xprev = (cg == 0) ? (valid ? x[127] : 0.f) : xpn;
        float y[8];
        y[0] = (v0.x - PRE * xprev - mc) * w0.x;
        y[1] = (v0.y - PRE * v0.x - mc) * w0.y;
        y[2] = (v0.z - PRE * v0.y - mc) * w0.z;
        y[3] = (v0.w - PRE * v0.z - mc) * w0.w;
        y[4] = (v1.x - PRE * v0.w - mc) * w1.x;
        y[5] = (v1.y - PRE * v1.x - mc) * w1.y;
        y[6] = (v1.z - PRE * v1.y - mc) * w1.z;
        y[7] = (v1.w - PRE * v1.z - mc) * w1.w;

        const int u0 = 384 - 8 * cg;        // 264..384, all fold
        float4 xr0 = {0,0,0,0}, xr1 = {0,0,0,0};
        float xu0 = 0.f;
        if (valid) { xr0 = x4[u0 / 4 - 2]; xr1 = x4[u0 / 4 - 1]; xu0 = x[u0]; }
        float4 wr0 = win4[u0 / 4 - 2], wr1 = win4[u0 / 4 - 1];
        float wu0 = win[u0];
        float yr[8];
        yr[0] = (xu0   - PRE * xr1.w - mc) * wu0;
        yr[1] = (xr1.w - PRE * xr1.z - mc) * wr1.w;
        yr[2] = (xr1.z - PRE * xr1.y - mc) * wr1.z;
        yr[3] = (xr1.y - PRE * xr1.x - mc) * wr1.y;
        yr[4] = (xr1.x - PRE * xr0.w - mc) * wr1.x;
        yr[5] = (xr0.w - PRE * xr0.z - mc) * wr0.w;
        yr[6] = (xr0.z - PRE * xr0.y - mc) * wr0.z;
        yr[7] = (xr0.y - PRE * xr0.x - mc) * wr0.y;

        float s8[8], d8[8];
        #pragma unroll
        for (int e = 0; e < 8; ++e) { s8[e] = y[e] + yr[e]; d8[e] = y[e] - yr[e]; }
        u32 byteS = (u32)rr * 320u + (((u32)cg * 16u) ^ ((((u32)rr >> 1) & 3u) << 4));
        u32 byteD = (u32)rr * 272u + (u32)cg * 16u;
        pack_write(s8, T + C1_SH, T + C1_SL, byteS);
        pack_write(d8, T + C1_DH, T + C1_DL, byteD);
    }
    // s tail: cols t=256..287 (units 16..19): only t=256 nonzero
    {
        const int rr = tid & 31;
        const int grp = tid >> 5;          // 0..7; units 16..19 served by grp<4
        if (grp < 4) {
            const int fr = f0 + rr;
            float y256 = 0.f;
            if (grp == 0 && fr < NFRAMES) {
                const float* x = wb + (size_t)fr * FS;
                y256 = (x[256] - PRE * x[255] - (1.0f - PRE) * smean[rr]) * win[256];
            }
            float s8[8] = {y256, 0.f, 0.f, 0.f, 0.f, 0.f, 0.f, 0.f};
            u32 byte = (u32)rr * 320u + ((((u32)(16 + grp)) * 16u) ^ ((((u32)rr >> 1) & 3u) << 4));
            pack_write(s8, T + C1_SH, T + C1_SL, byte);
        }
    }
    __syncthreads();

    // ---- GEMM chunk1: Re ks 4..8 (5 ks, A=s RS320 SWT1), Im ks 4..7 (A=d RS272) ----
    dft_pass<320, 1, 5, RE_KS>(T + C1_SH, T + C1_SL, wsb + OFF_REH, wsb + OFF_REL, 4, g, lane, accR);
    dft_pass<272, 2, 4, IM_KS>(T + C1_DH, T + C1_DL, wsb + OFF_IMH, wsb + OFF_IML, 4, g, lane, accI);
    __syncthreads();

    // ---- power -> LDS bf16 [32][256] (512-B stride, (r&7)<<4 XOR) ----
    #pragma unroll
    for (int mf = 0; mf < 2; ++mf)
        #pragma unroll
        for (int j = 0; j < 4; ++j)
            #pragma unroll
            for (int r = 0; r < 4; ++r) {
                float pR = accR[mf][j][r], pI = accI[mf][j][r];
                float pw = pR * pR + pI * pI;
                u32 row = (u32)(mf * 16 + (q << 2) + r);
                u32 bin = (u32)(64 * g + j * 16 + cg);
                u32 byte = (row * 512u + bin * 2u) ^ ((row & 7u) << 4);
                *(u16*)(T + byte) = f2bf(pw);
            }
    __syncthreads();

    // ---- mel GEMM (M=32, N=96 padded, K=256) + log epilogue ----
    const u16* melb = wsb + OFF_MEL;
    {
        const int mfm = w >> 1;            // rows mfm*16..+15
        const int nf0 = (w & 1) ? 3 : 0;   // frag trio {0,1,2} or {3,4,5(pad)}
        f32x4 accM[3];
        #pragma unroll
        for (int j = 0; j < 3; ++j) accM[j] = (f32x4)0.f;
        for (int ks = 0; ks < 8; ++ks) {
            u32 row = (u32)(mfm * 16 + cg);
            u32 byte = (row * 512u + (u32)(ks * 32 + (q << 3)) * 2u) ^ ((row & 7u) << 4);
            bf16x8 aP = *(const bf16x8*)(T + byte);
            #pragma unroll
            for (int j = 0; j < 3; ++j) {
                bf16x8 bM = *(const bf16x8*)(melb + ((size_t)((nf0 + j) * 8 + ks) * 64 + lane) * 8);
                accM[j] = __builtin_amdgcn_mfma_f32_16x16x32_bf16(aP, bM, accM[j], 0, 0, 0);
            }
        }
        #pragma unroll
        for (int j = 0; j < 3; ++j) {
            const int m = (nf0 + j) * 16 + cg;
            #pragma unroll
            for (int r = 0; r < 4; ++r) {
                const int rowl = mfm * 16 + (q << 2) + r;
                const int fr = f0 + rowl;
                if (fr < NFRAMES && m < NM) {
                    float v = fmaxf(accM[j][r] + EPSF, EPSF);
                    out[((size_t)b * NFRAMES + fr) * NM + m] = logf(v);
                }
            }
        }
    }
}

// ---------------- fallback (fp32 kernel, used if ws too small) ----------------
#define TFB 16
#define NB 256
__global__ __launch_bounds__(256, 3) void fbank_fallback(
    const float* __restrict__ wave, const float* __restrict__ win,
    const float* __restrict__ dftr, const float* __restrict__ dfti,
    const float* __restrict__ melw, float* __restrict__ out) {
    __shared__ float s_fr[TFB][PW];
    __shared__ float s_pw[TFB][NB + 1];
    const int tid = threadIdx.x, wv = tid >> 6, lane = tid & 63;
    const int fbase = blockIdx.x * TFB;
    #pragma unroll
    for (int j = 0; j < TFB / 4; ++j) {
        const int lf = wv * (TFB / 4) + j;
        const int gid = fbase + lf;
        const int bb = gid / NFRAMES;
        const int fr = gid - bb * NFRAMES;
        const float* x = wave + (size_t)bb * TLEN + (size_t)fr * FS;
        float s = 0.f;
        for (int i = lane; i < FL; i += 64) s += x[i];
        #pragma unroll
        for (int off = 32; off >= 1; off >>= 1) s += __shfl_xor(s, off);
        const float mean = s * (1.0f / FL);
        for (int i = lane; i < FL; i += 64) {
            const float xi = x[i];
            const float xm = (i == 0) ? xi : x[i - 1];
            s_fr[lf][i] = (xi - PRE * xm - (1.0f - PRE) * mean) * win[i];
        }
        for (int i = FL + lane; i < PW; i += 64) s_fr[lf][i] = 0.f;
    }
    __syncthreads();
    {
        const int bin = tid;
        const float4* dr4 = (const float4*)(dftr + (size_t)bin * PW);
        const float4* di4 = (const float4*)(dfti + (size_t)bin * PW);
        float accr[TFB], acci[TFB];
        #pragma unroll
        for (int f = 0; f < TFB; ++f) { accr[f] = 0.f; acci[f] = 0.f; }
        for (int k4 = 0; k4 < PW / 4; ++k4) {
            const float4 r = dr4[k4], im = di4[k4];
            #pragma unroll
            for (int f = 0; f < TFB; ++f) {
                const float4 fr = *(const float4*)&s_fr[f][k4 * 4];
                accr[f] += fr.x * r.x + fr.y * r.y + fr.z * r.z + fr.w * r.w;
                acci[f] += fr.x * im.x + fr.y * im.y + fr.z * im.z + fr.w * im.w;
            }
        }
        #pragma unroll
        for (int f = 0; f < TFB; ++f) s_pw[f][bin] = accr[f] * accr[f] + acci[f] * acci[f];
    }
    __syncthreads();
    for (int o = tid; o < TFB * NM; o += 256) {
        const int f = o / NM, m = o - f * NM;
        const float* wm = melw + (size_t)m * 257;
        float acc = 0.f;
        for (int k = 0; k < NB; ++k) acc += s_pw[f][k] * wm[k];
        out[(size_t)(fbase + f) * NM + m] = logf(fmaxf(acc + EPSF, EPSF));
    }
}

extern "C" void kernel_launch(void* const* d_in, const int* in_sizes, int n_in,
                              void* d_out, int out_size, void* d_ws, size_t ws_size,
                              hipStream_t stream) {
    const float* wave = (const float*)d_in[0];
    const float* win  = (const float*)d_in[1];
    const float* dftr = (const float*)d_in[2];
    const float* dfti = (const float*)d_in[3];
    const float* melw = (const float*)d_in[4];
    float* out = (float*)d_out;

    if (ws_size >= WS_NEED) {
        u16* wsb = (u16*)d_ws;
        const int prep_threads = 16 * RE_KS * 64 + 16 * IM_KS * 64 + 6 * 8 * 64;  // 20480
        prep_kernel<<<(prep_threads + 255) / 256, 256, 0, stream>>>(dftr, dfti, melw, wsb);
        dim3 grid(NTILES, BATCH);
        fbank_mfma<<<grid, 256, 0, stream>>>(wave, win, wsb, out);
    } else {
        const int nblocks = (BATCH * NFRAMES) / TFB;
        fbank_fallback<<<nblocks, 256, 0, stream>>>(wave, win, dftr, dfti, melw, out);
    }
}

// Round 12
// 126.316 us; speedup vs baseline: 1.1001x; 1.1001x over previous
//
#include <hip/hip_runtime.h>
#include <math.h>

// Fbank via split-bf16 MFMA + real-DFT folding. R12 = R11 + restored B-fragment
// software pipelining in dft_pass (R7-style ping-pong: next (ks,j) B group is
// issued before the current group's 6 MFMAs -> L2 latency covered), and the
// means->P1b barrier removed (mean kept in registers via 16-lane shfl).

#define BATCH 32
#define TLEN 480000
#define NFRAMES 2998
#define FL 400
#define FS 160
#define PW 512
#define NM 80
#define MT 32                // frames per block
#define NTILES 94            // ceil(2998/32)
#define PRE 0.97f
#define EPSF 1e-6f

#define RE_KS 9              // K=288 (t 0..256 + pad)
#define IM_KS 8              // K=256 (t 0..255)
#define RE_U16 (16 * RE_KS * 64 * 8)   // 73728
#define IM_U16 (16 * IM_KS * 64 * 8)   // 65536
#define MEL_U16 (6 * 8 * 64 * 8)       // 24576
#define OFF_REH 0
#define OFF_REL RE_U16
#define OFF_IMH (2 * RE_U16)
#define OFF_IML (2 * RE_U16 + IM_U16)
#define OFF_MEL (2 * RE_U16 + 2 * IM_U16)
#define WS_NEED ((size_t)(OFF_MEL + MEL_U16) * 2)   // 606,208 B

// LDS tile byte offsets. 128-col tiles: 272-B row stride (natural bank
// rotation, no XOR). 160-col chunk1 s-tile: 320-B stride + SWT1 XOR.
#define C0_SH 0
#define C0_SL 8704
#define C0_DH 17408
#define C0_DL 26112          // chunk0 total 34,816 B
#define C1_SH 0
#define C1_SL 10240
#define C1_DH 20480
#define C1_DL 29184          // chunk1 total 37,888 B

typedef short bf16x8 __attribute__((ext_vector_type(8)));
typedef float f32x4 __attribute__((ext_vector_type(4)));
typedef unsigned int u32;
typedef unsigned short u16;
typedef u32 u32x4 __attribute__((ext_vector_type(4)));

__device__ __forceinline__ u16 f2bf(float f) {
    u32 u = __builtin_bit_cast(u32, f);
    return (u16)((u + 0x7FFFu + ((u >> 16) & 1u)) >> 16);
}
__device__ __forceinline__ float bf2f(u16 h) {
    u32 u = ((u32)h) << 16;
    return __builtin_bit_cast(float, u);
}

// ---------------- prep: pack folded B (cos K=288, sin K=256, hi+lo) + mel ----------------
__global__ void prep_kernel(const float* __restrict__ dftr, const float* __restrict__ dfti,
                            const float* __restrict__ melw, u16* __restrict__ wsb) {
    int idx = blockIdx.x * 256 + threadIdx.x;
    if (idx < 16 * RE_KS * 64) {                       // 9216 Re groups
        int nf = idx / (RE_KS * 64);
        int rem = idx - nf * (RE_KS * 64);
        int ks = rem >> 6, l = rem & 63;
        int f = nf * 16 + (l & 15);
        int k = ks * 32 + ((l >> 4) << 3);
        u16* dh = wsb + OFF_REH + (size_t)idx * 8;
        u16* dl = wsb + OFF_REL + (size_t)idx * 8;
        #pragma unroll
        for (int e = 0; e < 8; ++e) {
            int kk = k + e;
            float x = (kk <= 256) ? dftr[(size_t)f * PW + kk] : 0.f;
            u16 h = f2bf(x);
            dh[e] = h;
            dl[e] = f2bf(x - bf2f(h));
        }
    } else if (idx < 16 * RE_KS * 64 + 16 * IM_KS * 64) {   // 8192 Im groups
        int j = idx - 16 * RE_KS * 64;
        int nf = j / (IM_KS * 64);
        int rem = j - nf * (IM_KS * 64);
        int ks = rem >> 6, l = rem & 63;
        int f = nf * 16 + (l & 15);
        int k = ks * 32 + ((l >> 4) << 3);
        u16* dh = wsb + OFF_IMH + (size_t)j * 8;
        u16* dl = wsb + OFF_IML + (size_t)j * 8;
        #pragma unroll
        for (int e = 0; e < 8; ++e) {
            float x = dfti[(size_t)f * PW + k + e];    // k+e <= 255
            u16 h = f2bf(x);
            dh[e] = h;
            dl[e] = f2bf(x - bf2f(h));
        }
    } else {                                            // 3072 mel groups
        int m = idx - (16 * RE_KS * 64 + 16 * IM_KS * 64);
        if (m < 6 * 8 * 64) {
            int nf = m / (8 * 64);
            int ks = (m >> 6) & 7, l = m & 63;
            int n = nf * 16 + (l & 15);
            int k = ks * 32 + ((l >> 4) << 3);
            u16* dst = wsb + OFF_MEL + (size_t)m * 8;
            #pragma unroll
            for (int e = 0; e < 8; ++e)
                dst[e] = (n < NM) ? f2bf(melw[(size_t)n * 257 + k + e]) : (u16)0;
        }
    }
}

// swizzle select: 0 -> (r&7)<<4 (512-B stride), 1 -> ((r>>1)&3)<<4 (320-B), 2 -> none (272-B)
__device__ __forceinline__ u32 swz(int SWT, u32 r) {
    return (SWT == 0) ? ((r & 7u) << 4) : (SWT == 1) ? (((r >> 1) & 3u) << 4) : 0u;
}

// 6 MFMA for one (bh,bl) ping-pong slot: 2 m-frags x 3 split-product terms
#define MFMA6(D, J)                                                                        \
    _Pragma("unroll")                                                                      \
    for (int mf = 0; mf < 2; ++mf) {                                                       \
        acc[mf][J] = __builtin_amdgcn_mfma_f32_16x16x32_bf16(aH[mf], D[0], acc[mf][J], 0, 0, 0); \
        acc[mf][J] = __builtin_amdgcn_mfma_f32_16x16x32_bf16(aL[mf], D[0], acc[mf][J], 0, 0, 0); \
        acc[mf][J] = __builtin_amdgcn_mfma_f32_16x16x32_bf16(aH[mf], D[1], acc[mf][J], 0, 0, 0); \
    }

// ---------------- DFT pass: split product, B ping-pong prefetch ----------------
template<int RS, int SWT, int NKS, int BKS>
__device__ __forceinline__ void dft_pass(
    const char* tH, const char* tL,
    const u16* __restrict__ bH, const u16* __restrict__ bL,
    int ks0, int g, int lane, f32x4 (&acc)[2][4]) {

    bf16x8 aH[2], aL[2], Ba[2], Bb[2];

#define LDA_P(KS)                                                              \
    { _Pragma("unroll")                                                        \
      for (int mf = 0; mf < 2; ++mf) {                                         \
        u32 r = (u32)(mf * 16 + (lane & 15));                                  \
        u32 off = (u32)((KS) * 64 + ((lane >> 4) << 4));                       \
        u32 byte = r * RS + (off ^ swz(SWT, r));                               \
        aH[mf] = *(const bf16x8*)(tH + byte);                                  \
        aL[mf] = *(const bf16x8*)(tL + byte);                                  \
      } }
#define LDB_P(KSG, J, D)                                                       \
    {                                                                          \
        size_t o = ((size_t)((4 * g + (J)) * BKS + (KSG)) * 64 + lane) * 8;    \
        D[0] = *(const bf16x8*)(bH + o);                                       \
        D[1] = *(const bf16x8*)(bL + o);                                       \
    }

    LDB_P(ks0, 0, Ba);
    #pragma unroll
    for (int ks = 0; ks < NKS; ++ks) {
        LDA_P(ks);
        LDB_P(ks0 + ks, 1, Bb);
        MFMA6(Ba, 0);
        LDB_P(ks0 + ks, 2, Ba);
        MFMA6(Bb, 1);
        LDB_P(ks0 + ks, 3, Bb);
        MFMA6(Ba, 2);
        if (ks + 1 < NKS) LDB_P(ks0 + ks + 1, 0, Ba);
        MFMA6(Bb, 3);
    }
#undef LDA_P
#undef LDB_P
}

__device__ __forceinline__ void pack_write(const float* ys, char* baseH, char* baseL, u32 byte) {
    u32x4 hv, lv;
    #pragma unroll
    for (int e = 0; e < 4; ++e) {
        u16 h0 = f2bf(ys[2 * e]), h1 = f2bf(ys[2 * e + 1]);
        hv[e] = (u32)h0 | ((u32)h1 << 16);
        u16 l0 = f2bf(ys[2 * e] - bf2f(h0)), l1 = f2bf(ys[2 * e + 1] - bf2f(h1));
        lv[e] = (u32)l0 | ((u32)l1 << 16);
    }
    *(u32x4*)(baseH + byte) = hv;
    *(u32x4*)(baseL + byte) = lv;
}

// ---------------- main fused kernel ----------------
__global__ __launch_bounds__(256, 3) void fbank_mfma(
    const float* __restrict__ wave, const float* __restrict__ win,
    const u16* __restrict__ wsb, float* __restrict__ out) {
    __shared__ float smean[MT];
    __shared__ u16 stile[18944];       // 37,888 B tile buffer (power overlay fits)
    char* T = (char*)stile;

    const int tid = threadIdx.x, w = tid >> 6, lane = tid & 63;
    const int q = lane >> 4;           // frame sub-row within step
    const int cg = lane & 15;          // col-group
    const int b = blockIdx.y;
    const int f0 = blockIdx.x * MT;
    const float* wb = wave + (size_t)b * TLEN;
    const float4* win4 = (const float4*)win;

    // ---- means: kept in registers (16-lane shfl broadcast); LDS copy for the tail ----
    float mean[2];
    #pragma unroll
    for (int i = 0; i < 2; ++i) {
        const int rr = w * 8 + i * 4 + q;
        const int fr = f0 + rr;
        float acc = 0.f;
        if (fr < NFRAMES) {
            const float4* x4 = (const float4*)(wb + (size_t)fr * FS);
            #pragma unroll
            for (int m = 0; m < 6; ++m) {
                float4 a = x4[cg + 16 * m];
                acc += a.x + a.y + a.z + a.w;
            }
            if (cg < 4) { float4 a = x4[96 + cg]; acc += a.x + a.y + a.z + a.w; }
        }
        #pragma unroll
        for (int o = 8; o; o >>= 1) acc += __shfl_xor(acc, o);
        mean[i] = acc * (1.0f / FL);
        if (cg == 0) smean[rr] = mean[i];
    }
    // no barrier: each wave only uses its own mean[] below; smean read after later barriers

    // ---- P1b: chunk0 (t 0..127): build s,d tiles (272-B stride, no XOR) ----
    #pragma unroll
    for (int i = 0; i < 2; ++i) {
        const int rr = w * 8 + i * 4 + q;
        const int fr = f0 + rr;
        const bool valid = fr < NFRAMES;
        const float* x = wb + (size_t)fr * FS;
        const float4* x4 = (const float4*)x;
        const float mc = (1.0f - PRE) * mean[i];

        float4 v0 = {0,0,0,0}, v1 = {0,0,0,0};
        if (valid) { v0 = x4[2 * cg]; v1 = x4[2 * cg + 1]; }
        float4 w0 = win4[2 * cg], w1 = win4[2 * cg + 1];
        float xpn = __shfl(v1.w, lane - 1);
        float xprev = (cg == 0) ? v0.x : xpn;
        float y[8];
        y[0] = (v0.x - PRE * xprev - mc) * w0.x;
        y[1] = (v0.y - PRE * v0.x - mc) * w0.y;
        y[2] = (v0.z - PRE * v0.y - mc) * w0.z;
        y[3] = (v0.w - PRE * v0.z - mc) * w0.w;
        y[4] = (v1.x - PRE * v0.w - mc) * w1.x;
        y[5] = (v1.y - PRE * v1.x - mc) * w1.y;
        y[6] = (v1.z - PRE * v1.y - mc) * w1.z;
        y[7] = (v1.w - PRE * v1.z - mc) * w1.w;

        float yr[8];
        #pragma unroll
        for (int e = 0; e < 8; ++e) yr[e] = 0.f;
        if (cg >= 14) {                      // t >= 113 folds (u = 512-t in 385..399)
            const int u0 = 512 - 8 * cg;     // 400 (cg14) or 392 (cg15)
            float4 xr0 = {0,0,0,0}, xr1 = {0,0,0,0};
            float xu0 = 0.f;
            if (valid) {
                xr0 = x4[u0 / 4 - 2]; xr1 = x4[u0 / 4 - 1];
                if (u0 <= 399) xu0 = x[u0];
            }
            float4 wr0 = win4[u0 / 4 - 2], wr1 = win4[u0 / 4 - 1];
            float wu0 = (u0 <= 399) ? win[u0] : 0.f;
            yr[0] = (xu0   - PRE * xr1.w - mc) * wu0;
            yr[1] = (xr1.w - PRE * xr1.z - mc) * wr1.w;
            yr[2] = (xr1.z - PRE * xr1.y - mc) * wr1.z;
            yr[3] = (xr1.y - PRE * xr1.x - mc) * wr1.y;
            yr[4] = (xr1.x - PRE * xr0.w - mc) * wr1.x;
            yr[5] = (xr0.w - PRE * xr0.z - mc) * wr0.w;
            yr[6] = (xr0.z - PRE * xr0.y - mc) * wr0.z;
            yr[7] = (xr0.y - PRE * xr0.x - mc) * wr0.y;
        }
        float s8[8], d8[8];
        #pragma unroll
        for (int e = 0; e < 8; ++e) { s8[e] = y[e] + yr[e]; d8[e] = y[e] - yr[e]; }
        u32 byte = (u32)rr * 272u + (u32)cg * 16u;
        pack_write(s8, T + C0_SH, T + C0_SL, byte);
        pack_write(d8, T + C0_DH, T + C0_DL, byte);
    }
    __syncthreads();

    // ---- GEMM chunk0: Re ks 0..3 (A=s), Im ks 0..3 (A=d) ----
    const int g = w;
    f32x4 accR[2][4], accI[2][4];
    #pragma unroll
    for (int mf = 0; mf < 2; ++mf)
        #pragma unroll
        for (int j = 0; j < 4; ++j) { accR[mf][j] = (f32x4)0.f; accI[mf][j] = (f32x4)0.f; }

    dft_pass<272, 2, 4, RE_KS>(T + C0_SH, T + C0_SL, wsb + OFF_REH, wsb + OFF_REL, 0, g, lane, accR);
    dft_pass<272, 2, 4, IM_KS>(T + C0_DH, T + C0_DL, wsb + OFF_IMH, wsb + OFF_IML, 0, g, lane, accI);
    __syncthreads();

    // ---- P1c: chunk1 (t 128..255 fold; s also t 256..287 tail) ----
    #pragma unroll
    for (int i = 0; i < 2; ++i) {
        const int rr = w * 8 + i * 4 + q;
        const int fr = f0 + rr;
        const bool valid = fr < NFRAMES;
        const float* x = wb + (size_t)fr * FS;
        const float4* x4 = (const float4*)x;
        const float mc = (1.0f - PRE) * mean[i];

        float4 v0 = {0,0,0,0}, v1 = {0,0,0,0};
        if (valid) { v0 = x4[32 + 2 * cg]; v1 = x4[33 + 2 * cg]; }
        float4 w0 = win4[32 + 2 * cg], w1 = win4[33 + 2 * cg];
        float xpn = __shfl(v1.w, lane - 1);
        float xprev = (cg == 0) ? (valid ? x[127] : 0.f) : xpn;
        float y[8];
        y[0] = (v0.x - PRE * xprev - mc) * w0.x;
        y[1] = (v0.y - PRE * v0.x - mc) * w0.y;
        y[2] = (v0.z - PRE * v0.y - mc) * w0.z;
        y[3] = (v0.w - PRE * v0.z - mc) * w0.w;
        y[4] = (v1.x - PRE * v0.w - mc) * w1.x;
        y[5] = (v1.y - PRE * v1.x - mc) * w1.y;
        y[6] = (v1.z - PRE * v1.y - mc) * w1.z;
        y[7] = (v1.w - PRE * v1.z - mc) * w1.w;

        const int u0 = 384 - 8 * cg;        // 264..384, all fold
        float4 xr0 = {0,0,0,0}, xr1 = {0,0,0,0};
        float xu0 = 0.f;
        if (valid) { xr0 = x4[u0 / 4 - 2]; xr1 = x4[u0 / 4 - 1]; xu0 = x[u0]; }
        float4 wr0 = win4[u0 / 4 - 2], wr1 = win4[u0 / 4 - 1];
        float wu0 = win[u0];
        float yr[8];
        yr[0] = (xu0   - PRE * xr1.w - mc) * wu0;
        yr[1] = (xr1.w - PRE * xr1.z - mc) * wr1.w;
        yr[2] = (xr1.z - PRE * xr1.y - mc) * wr1.z;
        yr[3] = (xr1.y - PRE * xr1.x - mc) * wr1.y;
        yr[4] = (xr1.x - PRE * xr0.w - mc) * wr1.x;
        yr[5] = (xr0.w - PRE * xr0.z - mc) * wr0.w;
        yr[6] = (xr0.z - PRE * xr0.y - mc) * wr0.z;
        yr[7] = (xr0.y - PRE * xr0.x - mc) * wr0.y;

        float s8[8], d8[8];
        #pragma unroll
        for (int e = 0; e < 8; ++e) { s8[e] = y[e] + yr[e]; d8[e] = y[e] - yr[e]; }
        u32 byteS = (u32)rr * 320u + (((u32)cg * 16u) ^ ((((u32)rr >> 1) & 3u) << 4));
        u32 byteD = (u32)rr * 272u + (u32)cg * 16u;
        pack_write(s8, T + C1_SH, T + C1_SL, byteS);
        pack_write(d8, T + C1_DH, T + C1_DL, byteD);
    }
    // s tail: cols t=256..287 (units 16..19): only t=256 nonzero
    {
        const int rr = tid & 31;
        const int grp = tid >> 5;          // 0..7; units 16..19 served by grp<4
        if (grp < 4) {
            const int fr = f0 + rr;
            float y256 = 0.f;
            if (grp == 0 && fr < NFRAMES) {
                const float* x = wb + (size_t)fr * FS;
                y256 = (x[256] - PRE * x[255] - (1.0f - PRE) * smean[rr]) * win[256];
            }
            float s8[8] = {y256, 0.f, 0.f, 0.f, 0.f, 0.f, 0.f, 0.f};
            u32 byte = (u32)rr * 320u + ((((u32)(16 + grp)) * 16u) ^ ((((u32)rr >> 1) & 3u) << 4));
            pack_write(s8, T + C1_SH, T + C1_SL, byte);
        }
    }
    __syncthreads();

    // ---- GEMM chunk1: Re ks 4..8 (5 ks, A=s RS320 SWT1), Im ks 4..7 (A=d RS272) ----
    dft_pass<320, 1, 5, RE_KS>(T + C1_SH, T + C1_SL, wsb + OFF_REH, wsb + OFF_REL, 4, g, lane, accR);
    dft_pass<272, 2, 4, IM_KS>(T + C1_DH, T + C1_DL, wsb + OFF_IMH, wsb + OFF_IML, 4, g, lane, accI);
    __syncthreads();

    // ---- power -> LDS bf16 [32][256] (512-B stride, (r&7)<<4 XOR) ----
    #pragma unroll
    for (int mf = 0; mf < 2; ++mf)
        #pragma unroll
        for (int j = 0; j < 4; ++j)
            #pragma unroll
            for (int r = 0; r < 4; ++r) {
                float pR = accR[mf][j][r], pI = accI[mf][j][r];
                float pw = pR * pR + pI * pI;
                u32 row = (u32)(mf * 16 + (q << 2) + r);
                u32 bin = (u32)(64 * g + j * 16 + cg);
                u32 byte = (row * 512u + bin * 2u) ^ ((row & 7u) << 4);
                *(u16*)(T + byte) = f2bf(pw);
            }
    __syncthreads();

    // ---- mel GEMM (M=32, N=96 padded, K=256) + log epilogue ----
    const u16* melb = wsb + OFF_MEL;
    {
        const int mfm = w >> 1;            // rows mfm*16..+15
        const int nf0 = (w & 1) ? 3 : 0;   // frag trio {0,1,2} or {3,4,5(pad)}
        f32x4 accM[3];
        #pragma unroll
        for (int j = 0; j < 3; ++j) accM[j] = (f32x4)0.f;
        for (int ks = 0; ks < 8; ++ks) {
            u32 row = (u32)(mfm * 16 + cg);
            u32 byte = (row * 512u + (u32)(ks * 32 + (q << 3)) * 2u) ^ ((row & 7u) << 4);
            bf16x8 aP = *(const bf16x8*)(T + byte);
            #pragma unroll
            for (int j = 0; j < 3; ++j) {
                bf16x8 bM = *(const bf16x8*)(melb + ((size_t)((nf0 + j) * 8 + ks) * 64 + lane) * 8);
                accM[j] = __builtin_amdgcn_mfma_f32_16x16x32_bf16(aP, bM, accM[j], 0, 0, 0);
            }
        }
        #pragma unroll
        for (int j = 0; j < 3; ++j) {
            const int m = (nf0 + j) * 16 + cg;
            #pragma unroll
            for (int r = 0; r < 4; ++r) {
                const int rowl = mfm * 16 + (q << 2) + r;
                const int fr = f0 + rowl;
                if (fr < NFRAMES && m < NM) {
                    float v = fmaxf(accM[j][r] + EPSF, EPSF);
                    out[((size_t)b * NFRAMES + fr) * NM + m] = logf(v);
                }
            }
        }
    }
}

// ---------------- fallback (fp32 kernel, used if ws too small) ----------------
#define TFB 16
#define NB 256
__global__ __launch_bounds__(256, 3) void fbank_fallback(
    const float* __restrict__ wave, const float* __restrict__ win,
    const float* __restrict__ dftr, const float* __restrict__ dfti,
    const float* __restrict__ melw, float* __restrict__ out) {
    __shared__ float s_fr[TFB][PW];
    __shared__ float s_pw[TFB][NB + 1];
    const int tid = threadIdx.x, wv = tid >> 6, lane = tid & 63;
    const int fbase = blockIdx.x * TFB;
    #pragma unroll
    for (int j = 0; j < TFB / 4; ++j) {
        const int lf = wv * (TFB / 4) + j;
        const int gid = fbase + lf;
        const int bb = gid / NFRAMES;
        const int fr = gid - bb * NFRAMES;
        const float* x = wave + (size_t)bb * TLEN + (size_t)fr * FS;
        float s = 0.f;
        for (int i = lane; i < FL; i += 64) s += x[i];
        #pragma unroll
        for (int off = 32; off >= 1; off >>= 1) s += __shfl_xor(s, off);
        const float mean = s * (1.0f / FL);
        for (int i = lane; i < FL; i += 64) {
            const float xi = x[i];
            const float xm = (i == 0) ? xi : x[i - 1];
            s_fr[lf][i] = (xi - PRE * xm - (1.0f - PRE) * mean) * win[i];
        }
        for (int i = FL + lane; i < PW; i += 64) s_fr[lf][i] = 0.f;
    }
    __syncthreads();
    {
        const int bin = tid;
        const float4* dr4 = (const float4*)(dftr + (size_t)bin * PW);
        const float4* di4 = (const float4*)(dfti + (size_t)bin * PW);
        float accr[TFB], acci[TFB];
        #pragma unroll
        for (int f = 0; f < TFB; ++f) { accr[f] = 0.f; acci[f] = 0.f; }
        for (int k4 = 0; k4 < PW / 4; ++k4) {
            const float4 r = dr4[k4], im = di4[k4];
            #pragma unroll
            for (int f = 0; f < TFB; ++f) {
                const float4 fr = *(const float4*)&s_fr[f][k4 * 4];
                accr[f] += fr.x * r.x + fr.y * r.y + fr.z * r.z + fr.w * r.w;
                acci[f] += fr.x * im.x + fr.y * im.y + fr.z * im.z + fr.w * im.w;
            }
        }
        #pragma unroll
        for (int f = 0; f < TFB; ++f) s_pw[f][bin] = accr[f] * accr[f] + acci[f] * acci[f];
    }
    __syncthreads();
    for (int o = tid; o < TFB * NM; o += 256) {
        const int f = o / NM, m = o - f * NM;
        const float* wm = melw + (size_t)m * 257;
        float acc = 0.f;
        for (int k = 0; k < NB; ++k) acc += s_pw[f][k] * wm[k];
        out[(size_t)(fbase + f) * NM + m] = logf(fmaxf(acc + EPSF, EPSF));
    }
}

extern "C" void kernel_launch(void* const* d_in, const int* in_sizes, int n_in,
                              void* d_out, int out_size, void* d_ws, size_t ws_size,
                              hipStream_t stream) {
    const float* wave = (const float*)d_in[0];
    const float* win  = (const float*)d_in[1];
    const float* dftr = (const float*)d_in[2];
    const float* dfti = (const float*)d_in[3];
    const float* melw = (const float*)d_in[4];
    float* out = (float*)d_out;

    if (ws_size >= WS_NEED) {
        u16* wsb = (u16*)d_ws;
        const int prep_threads = 16 * RE_KS * 64 + 16 * IM_KS * 64 + 6 * 8 * 64;  // 20480
        prep_kernel<<<(prep_threads + 255) / 256, 256, 0, stream>>>(dftr, dfti, melw, wsb);
        dim3 grid(NTILES, BATCH);
        fbank_mfma<<<grid, 256, 0, stream>>>(wave, win, wsb, out);
    } else {
        const int nblocks = (BATCH * NFRAMES) / TFB;
        fbank_fallback<<<nblocks, 256, 0, stream>>>(wave, win, dftr, dfti, melw, out);
    }
}